// Round 9
// baseline (165.512 us; speedup 1.0000x reference)
//
#include <hip/hip_runtime.h>
#include <hip/hip_bf16.h>

#define N_PTS    262144
#define MB       64
#define NBLOCKS  (N_PTS / MB)     // 4096
#define NTHREADS 256

// ws layout (bf16 elements) — unchanged validated swizzle.
// Fragment f at ws[f*512 + lane*8 + j]; per-lane 16B contiguous -> weight
// loads are coalesced global_load_dwordx4 (1 KB/wave/instr), L2-resident.
#define WHS_OFF    8192           // W0: 2 ksteps * 8 ntiles * 512
#define WHS_STRIDE 24576          // per hidden layer: 6 * 8 * 512
#define WOUTS_OFF  131072         // 8192 + 5*24576
#define WS_TOTAL   137216         // + 4*3*512

typedef __bf16 bf16x8 __attribute__((ext_vector_type(8)));
typedef __bf16 bf16x4 __attribute__((ext_vector_type(4)));
typedef float  f32x4  __attribute__((ext_vector_type(4)));

// ---------------- weight pre-swizzle (unchanged, validated) ----------------
// Bias baked into K-pad row (W0 row 63 = b0, Wh row 191 = bh[L]); act pad col = 1.0.
__global__ __launch_bounds__(256) void prep_weights(
    const float* __restrict__ W0, const float* __restrict__ b0,
    const float* __restrict__ Wh, const float* __restrict__ bh,
    const float* __restrict__ Wout, __hip_bfloat16* __restrict__ ws)
{
    int d = blockIdx.x * 256 + threadIdx.x;
    if (d >= WS_TOTAL) return;
    int j    = d & 7;
    int lane = (d >> 3) & 63;
    int kin  = ((lane >> 4) & 3) * 8 + j;
    int nlo  = lane & 15;
    float val;
    if (d < WHS_OFF) {                       // W0: 63x128 + bias row 63
        int f = d >> 9;
        int k = (f >> 3) * 32 + kin;
        int n = (f & 7) * 16 + nlo;
        val = (k < 63) ? W0[k * 128 + n] : b0[n];
    } else if (d < WOUTS_OFF) {              // Wh[L]: 191x128 + bias row 191
        int local = d - WHS_OFF;
        int layer = local / WHS_STRIDE;
        int f = (local % WHS_STRIDE) >> 9;
        int k = (f >> 3) * 32 + kin;
        int n = (f & 7) * 16 + nlo;
        val = (k < 191) ? Wh[(layer * 191 + k) * 128 + n] : bh[layer * 128 + n];
    } else {                                 // Wout: 128x48 (bias in epilogue)
        int f = (d - WOUTS_OFF) >> 9;
        int k = (f / 3) * 32 + kin;
        int n = (f % 3) * 16 + nlo;
        val = Wout[k * 48 + n];
    }
    ws[d] = __float2bfloat16(val);
}

// ---------------- main fused kernel ----------------
// act layout: stride 192 bf16, XOR-swizzled at 16B-chunk granularity:
//   elem(row,col) = row*192 + (((col>>3) ^ (row&7))<<3) + (col&7)

__device__ __forceinline__ unsigned pack2bf(float a, float b)
{
    __hip_bfloat162 h = __float22bfloat162_rn(float2{a, b});
    return *reinterpret_cast<unsigned*>(&h);
}

// Retiled 4x2 (pg-split): A = weights (global, 4 mt frags = 64 units), B = act
// (LDS, 2 nf frags = 32 pts). Halves the block's LDS b-read traffic (the
// dominant pipe at ~67%); a-loads double but are L2-resident and L1-shared
// between the two waves of each ug. setprio(1) around each 8-MFMA cluster.
template<int KS>
__device__ __forceinline__ void mm_gw(
    const __hip_bfloat16* __restrict__ actb, int ptbase, int acol0, int ksbase,
    const __hip_bfloat16* __restrict__ wsrc, int ug,
    int m, int g, int lane, f32x4 (&acc)[4][2])
{
#pragma unroll
    for (int ks = 0; ks < KS; ++ks) {
        int col = acol0 + (ksbase + ks) * 32 + g * 8;      // multiple of 8
        int poff = (((col >> 3) ^ (m & 7)) << 3);
        bf16x8 a[4];
#pragma unroll
        for (int mt = 0; mt < 4; ++mt)
            a[mt] = *reinterpret_cast<const bf16x8*>(
                wsrc + (((ksbase + ks) * 8 + ug * 4 + mt) * 64 + lane) * 8);
        bf16x8 b[2];
#pragma unroll
        for (int nf = 0; nf < 2; ++nf)
            b[nf] = *reinterpret_cast<const bf16x8*>(
                actb + (ptbase + nf * 16 + m) * 192 + poff);
        __builtin_amdgcn_s_setprio(1);
#pragma unroll
        for (int mt = 0; mt < 4; ++mt)
#pragma unroll
            for (int nf = 0; nf < 2; ++nf)
                acc[mt][nf] = __builtin_amdgcn_mfma_f32_16x16x32_bf16(a[mt], b[nf], acc[mt][nf], 0, 0, 0);
        __builtin_amdgcn_s_setprio(0);
    }
}

__device__ __forceinline__ void zero_acc(f32x4 (&acc)[4][2])
{
#pragma unroll
    for (int i = 0; i < 4; ++i)
#pragma unroll
        for (int k = 0; k < 2; ++k)
            acc[i][k] = f32x4{0.f, 0.f, 0.f, 0.f};
}

// D point-major: lane (m,g) holds units (ug*4+mt)*16 + g*4 + {0..3} at point
// ptbase + nf*16 + m -> leaky + pack -> one 8B LDS write per fragment.
__device__ __forceinline__ void writeback_gw(__hip_bfloat16* actb, f32x4 (&acc)[4][2],
                                             int ptbase, int ug, int m, int g)
{
#pragma unroll
    for (int mt = 0; mt < 4; ++mt) {
        int chunk = (ug * 4 + mt) * 2 + (g >> 1);          // (unit col)>>3
#pragma unroll
        for (int nf = 0; nf < 2; ++nf) {
            int pt = ptbase + nf * 16 + m;
            float v0 = acc[mt][nf][0]; v0 = fmaxf(v0, 0.01f * v0);
            float v1 = acc[mt][nf][1]; v1 = fmaxf(v1, 0.01f * v1);
            float v2 = acc[mt][nf][2]; v2 = fmaxf(v2, 0.01f * v2);
            float v3 = acc[mt][nf][3]; v3 = fmaxf(v3, 0.01f * v3);
            uint2 pk; pk.x = pack2bf(v0, v1); pk.y = pack2bf(v2, v3);
            *reinterpret_cast<uint2*>(
                actb + pt * 192 + ((chunk ^ (pt & 7)) << 3) + (g & 1) * 4) = pk;
        }
    }
}

__global__ __launch_bounds__(NTHREADS, 4) void fused_kernel(
    const float* __restrict__ x, const float* __restrict__ view,
    const float* __restrict__ normal, const float* __restrict__ light,
    const float* __restrict__ bout, const __hip_bfloat16* __restrict__ ws,
    float* __restrict__ out)
{
    __shared__ __align__(16) __hip_bfloat16 s_act[MB * 192];   // 24576 B
    __shared__ __align__(16) __hip_bfloat16 chebt[MB * 16];    //  2048 B (bf16 T table)
    // total = 26624 B -> 6 blocks/CU, 24 waves/CU

    const int tid  = threadIdx.x;
    const int lane = tid & 63;
    const int wave = tid >> 6;
    const int m = lane & 15;
    const int g = lane >> 4;
    const int ug = wave & 1;         // unit group:  units [ug*64, +64)
    const int pg = wave >> 1;        // point group: pts   [pg*32, +32)
    const int ptbase = pg * 32;
    const int block0 = blockIdx.x * MB;

    // ---- geometry on wave 3 (tid 192..255), CONCURRENT with enc on waves 0-1 ----
    if (tid >= 192) {
        int pt  = tid - 192;
        int pid = block0 + pt;
        float nx = normal[pid*3+0], ny = normal[pid*3+1], nz = normal[pid*3+2];
        float vx = view[pid*3+0],   vy = view[pid*3+1],   vz = view[pid*3+2];
        float lx = light[pid*3+0],  ly = light[pid*3+1],  lz = light[pid*3+2];

        float inv = 1.f / fmaxf(sqrtf(nx*nx + ny*ny + nz*nz), 1e-6f);
        nx *= inv; ny *= inv; nz *= inv;
        float sgn = (nz >= 0.f) ? 1.f : -1.f;
        float s_z = sgn + nz;
        float safe = (fabsf(s_z) < 1e-6f) ? copysignf(1e-6f, s_z) : s_z;
        float a = -1.f / safe;
        float b = nx * ny * a;
        float sx = nx*nx*a*sgn + 1.f, sy = b*sgn, sz = -nx*sgn;
        inv = 1.f / fmaxf(sqrtf(sx*sx + sy*sy + sz*sz), 1e-6f); sx*=inv; sy*=inv; sz*=inv;
        float tx = sy*nz - sz*ny, ty = sz*nx - sx*nz, tz = sx*ny - sy*nx;
        inv = 1.f / fmaxf(sqrtf(tx*tx + ty*ty + tz*tz), 1e-6f); tx*=inv; ty*=inv; tz*=inv;
        sx = ny*tz - nz*ty; sy = nz*tx - nx*tz; sz = nx*ty - ny*tx;
        inv = 1.f / fmaxf(sqrtf(sx*sx + sy*sy + sz*sz), 1e-6f); sx*=inv; sy*=inv; sz*=inv;

        inv = 1.f / fmaxf(sqrtf(vx*vx + vy*vy + vz*vz), 1e-6f); vx*=inv; vy*=inv; vz*=inv;
        float wox = sx*vx + sy*vy + sz*vz;
        float woy = tx*vx + ty*vy + tz*vz;
        float woz = nx*vx + ny*vy + nz*vz;
        inv = 1.f / fmaxf(sqrtf(wox*wox + woy*woy + woz*woz), 1e-7f); wox*=inv; woy*=inv;
        float wix = sx*lx + sy*ly + sz*lz;
        float wiy = tx*lx + ty*ly + tz*lz;
        float wiz = nx*lx + ny*ly + nz*lz;
        inv = 1.f / fmaxf(sqrtf(wix*wix + wiy*wiy + wiz*wiz), 1e-7f); wix*=inv; wiy*=inv;
        float axn = -wix, ayn = -wiy;
        float num = axn*wox + ayn*woy;
        float den = sqrtf((axn*axn + ayn*ayn) * (wox*wox + woy*woy));
        float cp = fminf(fmaxf(num / den, -1.f), 1.f);

        chebt[pt*16 + 0] = __float2bfloat16(1.f);
        chebt[pt*16 + 1] = __float2bfloat16(cp);
        float t0 = 1.f, t1 = cp;
        for (int k = 2; k < 16; ++k) {
            float t2 = 2.f*cp*t1 - t0;
            chebt[pt*16 + k] = __float2bfloat16(t2);
            t0 = t1; t1 = t2;
        }
    }

    // ---- positional encoding, 2 threads per point (5 freqs each), swizzled store ----
    if (tid < 2 * MB) {
        int pt  = tid >> 1;
        int sub = tid & 1;
        int pid = block0 + pt;
        float px = x[pid*3+0], py = x[pid*3+1], pz = x[pid*3+2];
        const int sw = pt & 7;
        __hip_bfloat16* ar = &s_act[pt * 192];
#define ENC_ST(cidx, val) ar[(((((cidx)+128) >> 3) ^ sw) << 3) + (((cidx)+128) & 7)] = __float2bfloat16(val)
        if (sub == 0) {
            ENC_ST(0, px); ENC_ST(1, py); ENC_ST(2, pz);
        } else {
            ENC_ST(63, 1.0f);   // K-pad column = 1.0 -> bias row of weights
        }
#pragma unroll
        for (int ff = 0; ff < 5; ++ff) {
            int f = sub * 5 + ff;
            float fr = (float)(1 << f);
            float s0, c0, s1, c1, s2, c2;
            __sincosf(px * fr, &s0, &c0);
            __sincosf(py * fr, &s1, &c1);
            __sincosf(pz * fr, &s2, &c2);
            ENC_ST(3  + f*3 + 0, s0);
            ENC_ST(3  + f*3 + 1, s1);
            ENC_ST(3  + f*3 + 2, s2);
            ENC_ST(33 + f*3 + 0, c0);
            ENC_ST(33 + f*3 + 1, c1);
            ENC_ST(33 + f*3 + 2, c2);
        }
#undef ENC_ST
    }
    __syncthreads();                 // B1: enc + cheb visible

    // T values for the out-layer: this thread covers pt = wave*16+m, orders g*4..+3
    float4 T_reg;
    {
        bf16x4 tv = *reinterpret_cast<const bf16x4*>(&chebt[(wave * 16 + m) * 16 + g * 4]);
        T_reg.x = (float)tv[0];
        T_reg.y = (float)tv[1];
        T_reg.z = (float)tv[2];
        T_reg.w = (float)tv[3];
    }

    f32x4 acc[4][2];

    // ===== layer 0: enc(64) -> 128; reads cols 128..191, writes 0..127 (disjoint) =====
    zero_acc(acc);
    mm_gw<2>(s_act, ptbase, 128, 0, ws, ug, m, g, lane, acc);
    writeback_gw(s_act, acc, ptbase, ug, m, g);
    __syncthreads();                 // h visible

    // ===== 5 hidden layers: [h|enc|1](192) -> 128, weights straight from L2 =====
    // enc k-steps FIRST (immutable cols), then h k-steps: all 48 MFMAs form one
    // run and the two barriers are adjacent with only the writeback between.
    for (int L = 0; L < 5; ++L) {
        const __hip_bfloat16* wsrc = ws + WHS_OFF + L * WHS_STRIDE;
        zero_acc(acc);
        mm_gw<2>(s_act, ptbase, 0, 4, wsrc, ug, m, g, lane, acc);   // k 128..191 (enc, never rewritten)
        mm_gw<4>(s_act, ptbase, 0, 0, wsrc, ug, m, g, lane, acc);   // k 0..127 (h region)
        __syncthreads();             // all h-reads done before overwrite
        writeback_gw(s_act, acc, ptbase, ug, m, g);
        __syncthreads();             // new h visible
    }

    // ===== output layer: h(128) -> 48, weights from L2, fused Chebyshev =====
    {
        f32x4 oacc[3];
#pragma unroll
        for (int c = 0; c < 3; ++c) oacc[c] = f32x4{0.f, 0.f, 0.f, 0.f};
        const int ptb = wave * 16;
        const __hip_bfloat16* wo = ws + WOUTS_OFF;
#pragma unroll
        for (int ks = 0; ks < 4; ++ks) {
            int col = ks * 32 + g * 8;
            int poff = (((col >> 3) ^ (m & 7)) << 3);
            bf16x8 b = *reinterpret_cast<const bf16x8*>(s_act + (ptb + m) * 192 + poff);
#pragma unroll
            for (int c = 0; c < 3; ++c) {
                bf16x8 a = *reinterpret_cast<const bf16x8*>(wo + ((ks * 3 + c) * 64 + lane) * 8);
                oacc[c] = __builtin_amdgcn_mfma_f32_16x16x32_bf16(a, b, oacc[c], 0, 0, 0);
            }
        }

        // D rows = Chebyshev order o = g*4+r, cols = points. Contract with T, reduce over g.
#pragma unroll
        for (int c = 0; c < 3; ++c) {
            float partial = 0.f;
#pragma unroll
            for (int r = 0; r < 4; ++r)
                partial += (oacc[c][r] + bout[c * 16 + g * 4 + r]) * (&T_reg.x)[r];
            partial += __shfl_xor(partial, 16, 64);
            partial += __shfl_xor(partial, 32, 64);
            if (g == 0)
                out[(block0 + ptb + m) * 3 + c] = partial;
        }
    }
}

extern "C" void kernel_launch(void* const* d_in, const int* in_sizes, int n_in,
                              void* d_out, int out_size, void* d_ws, size_t ws_size,
                              hipStream_t stream)
{
    const float* x      = (const float*)d_in[0];
    const float* view   = (const float*)d_in[1];
    const float* normal = (const float*)d_in[2];
    const float* light  = (const float*)d_in[3];
    const float* W0     = (const float*)d_in[4];
    const float* b0     = (const float*)d_in[5];
    const float* Wh     = (const float*)d_in[6];
    const float* bh     = (const float*)d_in[7];
    const float* Wout   = (const float*)d_in[8];
    const float* bout   = (const float*)d_in[9];
    float* out = (float*)d_out;
    __hip_bfloat16* ws = (__hip_bfloat16*)d_ws;

    hipLaunchKernelGGL(prep_weights, dim3(WS_TOTAL / 256 + 1), dim3(256), 0, stream,
                       W0, b0, Wh, bh, Wout, ws);
    hipLaunchKernelGGL(fused_kernel, dim3(NBLOCKS), dim3(NTHREADS), 0, stream,
                       x, view, normal, light, bout, ws, out);
}

// Round 10
// 152.042 us; speedup vs baseline: 1.0886x; 1.0886x over previous
//
#include <hip/hip_runtime.h>
#include <hip/hip_bf16.h>

#define N_PTS    262144
#define MB       128
#define NBLOCKS  (N_PTS / MB)     // 2048
#define NTHREADS 256

// ws layout (bf16 elements) — unchanged validated swizzle.
#define WHS_OFF    8192           // W0: 2 ksteps * 8 ntiles * 512
#define WHS_STRIDE 24576          // per hidden layer: 6 * 8 * 512
#define WOUTS_OFF  131072         // 8192 + 5*24576
#define WS_TOTAL   137216         // + 4*3*512

typedef __bf16 bf16x8 __attribute__((ext_vector_type(8)));
typedef __bf16 bf16x4 __attribute__((ext_vector_type(4)));
typedef float  f32x4  __attribute__((ext_vector_type(4)));

// ---------------- weight pre-swizzle (unchanged, validated) ----------------
__global__ __launch_bounds__(256) void prep_weights(
    const float* __restrict__ W0, const float* __restrict__ b0,
    const float* __restrict__ Wh, const float* __restrict__ bh,
    const float* __restrict__ Wout, __hip_bfloat16* __restrict__ ws)
{
    int d = blockIdx.x * 256 + threadIdx.x;
    if (d >= WS_TOTAL) return;
    int j    = d & 7;
    int lane = (d >> 3) & 63;
    int kin  = ((lane >> 4) & 3) * 8 + j;
    int nlo  = lane & 15;
    float val;
    if (d < WHS_OFF) {                       // W0: 63x128 + bias row 63
        int f = d >> 9;
        int k = (f >> 3) * 32 + kin;
        int n = (f & 7) * 16 + nlo;
        val = (k < 63) ? W0[k * 128 + n] : b0[n];
    } else if (d < WOUTS_OFF) {              // Wh[L]: 191x128 + bias row 191
        int local = d - WHS_OFF;
        int layer = local / WHS_STRIDE;
        int f = (local % WHS_STRIDE) >> 9;
        int k = (f >> 3) * 32 + kin;
        int n = (f & 7) * 16 + nlo;
        val = (k < 191) ? Wh[(layer * 191 + k) * 128 + n] : bh[layer * 128 + n];
    } else {                                 // Wout: 128x48 (bias in epilogue)
        int f = (d - WOUTS_OFF) >> 9;
        int k = (f / 3) * 32 + kin;
        int n = (f % 3) * 16 + nlo;
        val = Wout[k * 48 + n];
    }
    ws[d] = __float2bfloat16(val);
}

// ---------------- main fused kernel ----------------
// act layout: stride 192 bf16, XOR-swizzled at 16B-chunk granularity:
//   elem(row,col) = row*192 + (((col>>3) ^ (row&7))<<3) + (col&7)

__device__ __forceinline__ unsigned pack2bf(float a, float b)
{
    __hip_bfloat162 h = __float22bfloat162_rn(float2{a, b});
    return *reinterpret_cast<unsigned*>(&h);
}

// 64x64 register tile: A = weights (global, 4 mt frags = 64 units), B = act
// (LDS, 4 nf frags = 64 pts). Each a-frag feeds 4 MFMAs and each b-frag feeds
// 4 MFMAs -> per-point LDS b-traffic HALVES vs the 32x64 tile while per-point
// global a-traffic is UNCHANGED (the quantity whose doubling killed R3/R9).
template<int KS>
__device__ __forceinline__ void mm_gw(
    const __hip_bfloat16* __restrict__ actb, int ptbase, int acol0, int ksbase,
    const __hip_bfloat16* __restrict__ wsrc, int ug,
    int m, int g, int lane, f32x4 (&acc)[4][4])
{
#pragma unroll
    for (int ks = 0; ks < KS; ++ks) {
        int col = acol0 + (ksbase + ks) * 32 + g * 8;      // multiple of 8
        int poff = (((col >> 3) ^ (m & 7)) << 3);
        bf16x8 a[4];
#pragma unroll
        for (int mt = 0; mt < 4; ++mt)
            a[mt] = *reinterpret_cast<const bf16x8*>(
                wsrc + (((ksbase + ks) * 8 + ug * 4 + mt) * 64 + lane) * 8);
        bf16x8 b[4];
#pragma unroll
        for (int nf = 0; nf < 4; ++nf)
            b[nf] = *reinterpret_cast<const bf16x8*>(
                actb + (ptbase + nf * 16 + m) * 192 + poff);
        __builtin_amdgcn_s_setprio(1);
#pragma unroll
        for (int mt = 0; mt < 4; ++mt)
#pragma unroll
            for (int nf = 0; nf < 4; ++nf)
                acc[mt][nf] = __builtin_amdgcn_mfma_f32_16x16x32_bf16(a[mt], b[nf], acc[mt][nf], 0, 0, 0);
        __builtin_amdgcn_s_setprio(0);
    }
}

__device__ __forceinline__ void zero_acc(f32x4 (&acc)[4][4])
{
#pragma unroll
    for (int i = 0; i < 4; ++i)
#pragma unroll
        for (int k = 0; k < 4; ++k)
            acc[i][k] = f32x4{0.f, 0.f, 0.f, 0.f};
}

// D point-major: lane (m,g) holds units (ug*4+mt)*16 + g*4 + {0..3} at point
// ptbase + nf*16 + m -> leaky + pack -> one 8B LDS write per fragment.
__device__ __forceinline__ void writeback_gw(__hip_bfloat16* actb, f32x4 (&acc)[4][4],
                                             int ptbase, int ug, int m, int g)
{
#pragma unroll
    for (int mt = 0; mt < 4; ++mt) {
        int chunk = (ug * 4 + mt) * 2 + (g >> 1);          // (unit col)>>3
#pragma unroll
        for (int nf = 0; nf < 4; ++nf) {
            int pt = ptbase + nf * 16 + m;
            float v0 = acc[mt][nf][0]; v0 = fmaxf(v0, 0.01f * v0);
            float v1 = acc[mt][nf][1]; v1 = fmaxf(v1, 0.01f * v1);
            float v2 = acc[mt][nf][2]; v2 = fmaxf(v2, 0.01f * v2);
            float v3 = acc[mt][nf][3]; v3 = fmaxf(v3, 0.01f * v3);
            uint2 pk; pk.x = pack2bf(v0, v1); pk.y = pack2bf(v2, v3);
            *reinterpret_cast<uint2*>(
                actb + pt * 192 + ((chunk ^ (pt & 7)) << 3) + (g & 1) * 4) = pk;
        }
    }
}

__global__ __launch_bounds__(NTHREADS, 3) void fused_kernel(
    const float* __restrict__ x, const float* __restrict__ view,
    const float* __restrict__ normal, const float* __restrict__ light,
    const float* __restrict__ bout, const __hip_bfloat16* __restrict__ ws,
    float* __restrict__ out)
{
    __shared__ __align__(16) __hip_bfloat16 s_act[MB * 192];   // 49152 B
    __shared__ __align__(16) __hip_bfloat16 chebt[MB * 16];    //  4096 B (bf16 T table)
    // total = 53248 B -> 3 blocks/CU, 12 waves/CU (TLP traded for halved LDS b-traffic)

    const int tid  = threadIdx.x;
    const int lane = tid & 63;
    const int wave = tid >> 6;
    const int m = lane & 15;
    const int g = lane >> 4;
    const int ug = wave & 1;         // unit group:  units [ug*64, +64)  (4 mt tiles)
    const int pg = wave >> 1;        // point group: pts   [pg*64, +64)  (4 nf tiles)
    const int ptbase = pg * 64;
    const int block0 = blockIdx.x * MB;

    // ---- geometry: frame + cos_phi -> bf16 Chebyshev table (tid 0..127) ----
    if (tid < MB) {
        int pid = block0 + tid;
        float nx = normal[pid*3+0], ny = normal[pid*3+1], nz = normal[pid*3+2];
        float vx = view[pid*3+0],   vy = view[pid*3+1],   vz = view[pid*3+2];
        float lx = light[pid*3+0],  ly = light[pid*3+1],  lz = light[pid*3+2];

        float inv = 1.f / fmaxf(sqrtf(nx*nx + ny*ny + nz*nz), 1e-6f);
        nx *= inv; ny *= inv; nz *= inv;
        float sgn = (nz >= 0.f) ? 1.f : -1.f;
        float s_z = sgn + nz;
        float safe = (fabsf(s_z) < 1e-6f) ? copysignf(1e-6f, s_z) : s_z;
        float a = -1.f / safe;
        float b = nx * ny * a;
        float sx = nx*nx*a*sgn + 1.f, sy = b*sgn, sz = -nx*sgn;
        inv = 1.f / fmaxf(sqrtf(sx*sx + sy*sy + sz*sz), 1e-6f); sx*=inv; sy*=inv; sz*=inv;
        float tx = sy*nz - sz*ny, ty = sz*nx - sx*nz, tz = sx*ny - sy*nx;
        inv = 1.f / fmaxf(sqrtf(tx*tx + ty*ty + tz*tz), 1e-6f); tx*=inv; ty*=inv; tz*=inv;
        sx = ny*tz - nz*ty; sy = nz*tx - nx*tz; sz = nx*ty - ny*tx;
        inv = 1.f / fmaxf(sqrtf(sx*sx + sy*sy + sz*sz), 1e-6f); sx*=inv; sy*=inv; sz*=inv;

        inv = 1.f / fmaxf(sqrtf(vx*vx + vy*vy + vz*vz), 1e-6f); vx*=inv; vy*=inv; vz*=inv;
        float wox = sx*vx + sy*vy + sz*vz;
        float woy = tx*vx + ty*vy + tz*vz;
        float woz = nx*vx + ny*vy + nz*vz;
        inv = 1.f / fmaxf(sqrtf(wox*wox + woy*woy + woz*woz), 1e-7f); wox*=inv; woy*=inv;
        float wix = sx*lx + sy*ly + sz*lz;
        float wiy = tx*lx + ty*ly + tz*lz;
        float wiz = nx*lx + ny*ly + nz*lz;
        inv = 1.f / fmaxf(sqrtf(wix*wix + wiy*wiy + wiz*wiz), 1e-7f); wix*=inv; wiy*=inv;
        float axn = -wix, ayn = -wiy;
        float num = axn*wox + ayn*woy;
        float den = sqrtf((axn*axn + ayn*ayn) * (wox*wox + woy*woy));
        float cp = fminf(fmaxf(num / den, -1.f), 1.f);

        chebt[tid*16 + 0] = __float2bfloat16(1.f);
        chebt[tid*16 + 1] = __float2bfloat16(cp);
        float t0 = 1.f, t1 = cp;
        for (int k = 2; k < 16; ++k) {
            float t2 = 2.f*cp*t1 - t0;
            chebt[tid*16 + k] = __float2bfloat16(t2);
            t0 = t1; t1 = t2;
        }
    }

    // ---- positional encoding, 2 threads per point (5 freqs each), swizzled store ----
    if (tid < 2 * MB) {              // all 256 threads at MB=128
        int pt  = tid >> 1;
        int sub = tid & 1;
        int pid = block0 + pt;
        float px = x[pid*3+0], py = x[pid*3+1], pz = x[pid*3+2];
        const int sw = pt & 7;
        __hip_bfloat16* ar = &s_act[pt * 192];
#define ENC_ST(cidx, val) ar[(((((cidx)+128) >> 3) ^ sw) << 3) + (((cidx)+128) & 7)] = __float2bfloat16(val)
        if (sub == 0) {
            ENC_ST(0, px); ENC_ST(1, py); ENC_ST(2, pz);
        } else {
            ENC_ST(63, 1.0f);   // K-pad column = 1.0 -> bias row of weights
        }
#pragma unroll
        for (int ff = 0; ff < 5; ++ff) {
            int f = sub * 5 + ff;
            float fr = (float)(1 << f);
            float s0, c0, s1, c1, s2, c2;
            __sincosf(px * fr, &s0, &c0);
            __sincosf(py * fr, &s1, &c1);
            __sincosf(pz * fr, &s2, &c2);
            ENC_ST(3  + f*3 + 0, s0);
            ENC_ST(3  + f*3 + 1, s1);
            ENC_ST(3  + f*3 + 2, s2);
            ENC_ST(33 + f*3 + 0, c0);
            ENC_ST(33 + f*3 + 1, c1);
            ENC_ST(33 + f*3 + 2, c2);
        }
#undef ENC_ST
    }
    __syncthreads();                 // B1: enc + cheb visible

    f32x4 acc[4][4];

    // ===== layer 0: enc(64) -> 128; reads cols 128..191, writes 0..127 (disjoint) =====
    zero_acc(acc);
    mm_gw<2>(s_act, ptbase, 128, 0, ws, ug, m, g, lane, acc);
    writeback_gw(s_act, acc, ptbase, ug, m, g);
    __syncthreads();                 // h visible

    // ===== 5 hidden layers: [h|enc|1](192) -> 128, weights straight from L2 =====
    // enc k-steps FIRST (immutable cols), then h: all 96 MFMAs form one run,
    // barriers adjacent with only the writeback between.
    for (int L = 0; L < 5; ++L) {
        const __hip_bfloat16* wsrc = ws + WHS_OFF + L * WHS_STRIDE;
        zero_acc(acc);
        mm_gw<2>(s_act, ptbase, 0, 4, wsrc, ug, m, g, lane, acc);   // k 128..191 (enc, never rewritten)
        mm_gw<4>(s_act, ptbase, 0, 0, wsrc, ug, m, g, lane, acc);   // k 0..127 (h region)
        __syncthreads();             // all h-reads done before overwrite
        writeback_gw(s_act, acc, ptbase, ug, m, g);
        __syncthreads();             // new h visible
    }

    // ===== output layer: h(128) -> 48, weights from L2, fused Chebyshev =====
    // 4 waves x 32 pts (2 pt-tiles each).
    {
        f32x4 oacc[3][2];
#pragma unroll
        for (int c = 0; c < 3; ++c)
#pragma unroll
            for (int nt = 0; nt < 2; ++nt)
                oacc[c][nt] = f32x4{0.f, 0.f, 0.f, 0.f};
        const int ptb = wave * 32;
        const __hip_bfloat16* wo = ws + WOUTS_OFF;
#pragma unroll
        for (int ks = 0; ks < 4; ++ks) {
            int col = ks * 32 + g * 8;
            int poff = (((col >> 3) ^ (m & 7)) << 3);
            bf16x8 b[2];
#pragma unroll
            for (int nt = 0; nt < 2; ++nt)
                b[nt] = *reinterpret_cast<const bf16x8*>(s_act + (ptb + nt * 16 + m) * 192 + poff);
#pragma unroll
            for (int c = 0; c < 3; ++c) {
                bf16x8 a = *reinterpret_cast<const bf16x8*>(wo + ((ks * 3 + c) * 64 + lane) * 8);
#pragma unroll
                for (int nt = 0; nt < 2; ++nt)
                    oacc[c][nt] = __builtin_amdgcn_mfma_f32_16x16x32_bf16(a, b[nt], oacc[c][nt], 0, 0, 0);
            }
        }

        // D rows = Chebyshev order o = g*4+r, cols = points. Contract with T, reduce over g.
#pragma unroll
        for (int nt = 0; nt < 2; ++nt) {
            int pt = ptb + nt * 16 + m;
            float4 T_reg;
            {
                bf16x4 tv = *reinterpret_cast<const bf16x4*>(&chebt[pt * 16 + g * 4]);
                T_reg.x = (float)tv[0];
                T_reg.y = (float)tv[1];
                T_reg.z = (float)tv[2];
                T_reg.w = (float)tv[3];
            }
#pragma unroll
            for (int c = 0; c < 3; ++c) {
                float partial = 0.f;
#pragma unroll
                for (int r = 0; r < 4; ++r)
                    partial += (oacc[c][nt][r] + bout[c * 16 + g * 4 + r]) * (&T_reg.x)[r];
                partial += __shfl_xor(partial, 16, 64);
                partial += __shfl_xor(partial, 32, 64);
                if (g == 0)
                    out[(block0 + pt) * 3 + c] = partial;
            }
        }
    }
}

extern "C" void kernel_launch(void* const* d_in, const int* in_sizes, int n_in,
                              void* d_out, int out_size, void* d_ws, size_t ws_size,
                              hipStream_t stream)
{
    const float* x      = (const float*)d_in[0];
    const float* view   = (const float*)d_in[1];
    const float* normal = (const float*)d_in[2];
    const float* light  = (const float*)d_in[3];
    const float* W0     = (const float*)d_in[4];
    const float* b0     = (const float*)d_in[5];
    const float* Wh     = (const float*)d_in[6];
    const float* bh     = (const float*)d_in[7];
    const float* Wout   = (const float*)d_in[8];
    const float* bout   = (const float*)d_in[9];
    float* out = (float*)d_out;
    __hip_bfloat16* ws = (__hip_bfloat16*)d_ws;

    hipLaunchKernelGGL(prep_weights, dim3(WS_TOTAL / 256 + 1), dim3(256), 0, stream,
                       W0, b0, Wh, bh, Wout, ws);
    hipLaunchKernelGGL(fused_kernel, dim3(NBLOCKS), dim3(NTHREADS), 0, stream,
                       x, view, normal, light, bout, ws, out);
}